// Round 17
// baseline (311.264 us; speedup 1.0000x reference)
//
#include <hip/hip_runtime.h>

#define NNODES 50000
#define NEDGES 600000
#define DH 128
#define SCAN_THREADS 512
#define SCAN_ELEMS 2048
#define SCAN_BLOCKS ((NNODES + SCAN_ELEMS - 1) / SCAN_ELEMS)   // 25

typedef __attribute__((ext_vector_type(8))) short bf16x8;
typedef __attribute__((ext_vector_type(4))) float f32x4;
typedef __attribute__((ext_vector_type(4))) _Float16 half4;
typedef __attribute__((ext_vector_type(2))) _Float16 half2v;

__device__ __forceinline__ ushort f2bf(float x) {
    uint u = __float_as_uint(x);
    uint r = (u + 0x7FFF + ((u >> 16) & 1)) >> 16;
    return (ushort)r;
}
__device__ __forceinline__ float bf2f(ushort h) {
    return __uint_as_float(((uint)h) << 16);
}

// ---------------- degree count (int atomics) ----------------
__global__ void deg_count(const int* __restrict__ src, const int* __restrict__ dst,
                          int* __restrict__ cnt_out, int* __restrict__ cnt_in, int E) {
    int i = blockIdx.x * blockDim.x + threadIdx.x;
    if (i < E) {
        atomicAdd(&cnt_out[src[i]], 1);
        atomicAdd(&cnt_in[dst[i]], 1);
    }
}

// ---------------- multi-block scan, phase 1: per-block sums ----------------
__global__ __launch_bounds__(SCAN_THREADS) void scan_sums(
        const int* __restrict__ counts, int* __restrict__ bsums, int N) {
    __shared__ int red[SCAN_THREADS / 64];
    int b = blockIdx.x, t = threadIdx.x;
    int base = b * SCAN_ELEMS + t * 4;
    int s = 0;
    if (base + 3 < N) {
        int4 v = *(const int4*)(counts + base);
        s = v.x + v.y + v.z + v.w;
    } else {
        for (int j = 0; j < 4; ++j) if (base + j < N) s += counts[base + j];
    }
#pragma unroll
    for (int off = 32; off > 0; off >>= 1) s += __shfl_down(s, off);
    if ((t & 63) == 0) red[t >> 6] = s;
    __syncthreads();
    if (t == 0) {
        int tot = 0;
#pragma unroll
        for (int w = 0; w < SCAN_THREADS / 64; ++w) tot += red[w];
        bsums[b] = tot;
    }
}

// ---------------- multi-block scan, phase 2: final exclusive offsets ----------------
__global__ __launch_bounds__(SCAN_THREADS) void scan_final(
        const int* __restrict__ counts, const int* __restrict__ bsums,
        int* __restrict__ off, int N, int nb) {
    __shared__ int lds[SCAN_THREADS];
    __shared__ int base_s;
    int b = blockIdx.x, t = threadIdx.x;
    if (t == 0) {
        int acc = 0;
        for (int i = 0; i < b; ++i) acc += bsums[i];
        base_s = acc;
    }
    int i0 = b * SCAN_ELEMS + t * 4;
    int v[4]; int s = 0;
#pragma unroll
    for (int j = 0; j < 4; ++j) {
        int idx = i0 + j;
        v[j] = (idx < N) ? counts[idx] : 0;
        s += v[j];
    }
    lds[t] = s;
    __syncthreads();
    for (int d = 1; d < SCAN_THREADS; d <<= 1) {
        int x = lds[t];
        int y = (t >= d) ? lds[t - d] : 0;
        __syncthreads();
        lds[t] = x + y;
        __syncthreads();
    }
    int excl = (t == 0) ? 0 : lds[t - 1];
    int run = base_s + excl;
#pragma unroll
    for (int j = 0; j < 4; ++j) {
        int idx = i0 + j;
        if (idx < N) off[idx] = run;
        run += v[j];
    }
    if (b == nb - 1 && t == SCAN_THREADS - 1) off[N] = run;
}

// ---------------- norms + cursor init ----------------
__global__ void inv_kernel(const int* __restrict__ cnt_out, const int* __restrict__ cnt_in,
                           const int* __restrict__ row_off, int* __restrict__ cursor,
                           float* __restrict__ out_inv, float* __restrict__ in_inv, int N) {
    int i = blockIdx.x * blockDim.x + threadIdx.x;
    if (i < N) {
        out_inv[i] = rsqrtf(fmaxf((float)cnt_out[i], 1.0f));
        in_inv[i]  = rsqrtf(fmaxf((float)cnt_in[i], 1.0f));
        cursor[i]  = row_off[i];
    }
}

// ---------------- scatter edges into dst-CSR ----------------
__global__ void scatter_kernel(const int* __restrict__ src, const int* __restrict__ dst,
                               int* __restrict__ cursor, int* __restrict__ csr_src, int E) {
    int i = blockIdx.x * blockDim.x + threadIdx.x;
    if (i < E) {
        int pos = atomicAdd(&cursor[dst[i]], 1);
        csr_src[pos] = src[i];
    }
}

// ---------------- W -> transposed bf16 hi/lo: WT[n][k] ----------------
__global__ void wconv(const float* __restrict__ W0, const float* __restrict__ W1,
                      const float* __restrict__ W2,
                      ushort* __restrict__ WThi, ushort* __restrict__ WTlo) {
    int t = blockIdx.x * blockDim.x + threadIdx.x;
    if (t >= 3 * DH * DH) return;
    int L = t >> 14;
    int idx = t & (DH * DH - 1);
    int n = idx >> 7;
    int k = idx & 127;
    const float* W = (L == 0) ? W0 : ((L == 1) ? W1 : W2);
    float w = W[k * DH + n];
    ushort hi = f2bf(w);
    float lof = w - bf2f(hi);
    WThi[t] = hi;
    WTlo[t] = f2bf(lof);
}

// ---------------- features fp32 -> fp16 ----------------
__global__ void f32_to_f16(const float* __restrict__ in, _Float16* __restrict__ out, int n4) {
    int i = blockIdx.x * blockDim.x + threadIdx.x;
    if (i < n4) {
        float4 v = ((const float4*)in)[i];
        half4 h = {(_Float16)v.x, (_Float16)v.y, (_Float16)v.z, (_Float16)v.w};
        ((half4*)out)[i] = h;
    }
}

// ---------------- SpMM (gather fp16), half-wave per dst row, unroll x2 ----------------
// agg[d] = in_inv[d] * sum_{s in N(d)} out_inv[s]*h[s]; emits split-bf16
__global__ __launch_bounds__(256) void spmm_csr(
        const _Float16* __restrict__ h, const int* __restrict__ row_off,
        const int* __restrict__ csr_src, const float* __restrict__ out_inv,
        const float* __restrict__ in_inv,
        ushort* __restrict__ Xhi, ushort* __restrict__ Xlo, int N) {
    int gw   = (blockIdx.x * blockDim.x + threadIdx.x) >> 6;
    int lane = threadIdx.x & 63;
    int half = lane >> 5;          // two rows per wave
    int l5   = lane & 31;          // 32 lanes x 8B = 256B row
    int row  = gw * 2 + half;
    if (row >= N) return;
    int start = row_off[row], end = row_off[row + 1];
    float4 acc0 = make_float4(0.f, 0.f, 0.f, 0.f);
    float4 acc1 = make_float4(0.f, 0.f, 0.f, 0.f);
    int e = start;
    for (; e + 2 <= end; e += 2) {
        int s0 = csr_src[e];
        int s1 = csr_src[e + 1];
        float sc0 = out_inv[s0];
        float sc1 = out_inv[s1];
        half4 v0 = ((const half4*)(h + (size_t)s0 * DH))[l5];
        half4 v1 = ((const half4*)(h + (size_t)s1 * DH))[l5];
        acc0.x += (float)v0.x * sc0; acc0.y += (float)v0.y * sc0;
        acc0.z += (float)v0.z * sc0; acc0.w += (float)v0.w * sc0;
        acc1.x += (float)v1.x * sc1; acc1.y += (float)v1.y * sc1;
        acc1.z += (float)v1.z * sc1; acc1.w += (float)v1.w * sc1;
    }
    if (e < end) {
        int s0 = csr_src[e];
        float sc0 = out_inv[s0];
        half4 v0 = ((const half4*)(h + (size_t)s0 * DH))[l5];
        acc0.x += (float)v0.x * sc0; acc0.y += (float)v0.y * sc0;
        acc0.z += (float)v0.z * sc0; acc0.w += (float)v0.w * sc0;
    }
    float ii = in_inv[row];
    float4 acc;
    acc.x = (acc0.x + acc1.x) * ii;
    acc.y = (acc0.y + acc1.y) * ii;
    acc.z = (acc0.z + acc1.z) * ii;
    acc.w = (acc0.w + acc1.w) * ii;

    ushort4 hi, lo;
    hi.x = f2bf(acc.x); lo.x = f2bf(acc.x - bf2f(hi.x));
    hi.y = f2bf(acc.y); lo.y = f2bf(acc.y - bf2f(hi.y));
    hi.z = f2bf(acc.z); lo.z = f2bf(acc.z - bf2f(hi.z));
    hi.w = f2bf(acc.w); lo.w = f2bf(acc.w - bf2f(hi.w));
    ((ushort4*)(Xhi + (size_t)row * DH))[l5] = hi;
    ((ushort4*)(Xlo + (size_t)row * DH))[l5] = lo;
}

// ---------------- MFMA GEMM: Yf16 = relu(X @ W + b), split-bf16 3-pass ----------------
template<int RELU>
__global__ __launch_bounds__(256, 2) void gemm_mfma(
        const ushort* __restrict__ Xhi, const ushort* __restrict__ Xlo,
        const ushort* __restrict__ WThi, const ushort* __restrict__ WTlo,
        const float* __restrict__ bias, _Float16* __restrict__ Y, int Mtiles) {
    int lane  = threadIdx.x & 63;
    int gwave = (blockIdx.x * blockDim.x + threadIdx.x) >> 6;
    int nwav  = (gridDim.x * blockDim.x) >> 6;
    int nhalf = gwave & 1;
    int wstart  = gwave >> 1;
    int wstride = nwav >> 1;

    int r  = lane & 15;
    int kq = lane >> 4;

    bf16x8 B[2][4][4];
#pragma unroll
    for (int nt = 0; nt < 4; ++nt) {
        int n = 64 * nhalf + 16 * nt + r;
#pragma unroll
        for (int kf = 0; kf < 4; ++kf) {
            B[0][nt][kf] = *(const bf16x8*)(WThi + n * DH + 32 * kf + 8 * kq);
            B[1][nt][kf] = *(const bf16x8*)(WTlo + n * DH + 32 * kf + 8 * kq);
        }
    }
    float bs[4];
#pragma unroll
    for (int nt = 0; nt < 4; ++nt) bs[nt] = bias[64 * nhalf + 16 * nt + r];

    for (int mt = wstart; mt < Mtiles; mt += wstride) {
        int m0 = mt * 16;
        const ushort* xh = Xhi + (size_t)(m0 + r) * DH + 8 * kq;
        const ushort* xl = Xlo + (size_t)(m0 + r) * DH + 8 * kq;
        bf16x8 Ah[4], Al[4];
#pragma unroll
        for (int kf = 0; kf < 4; ++kf) {
            Ah[kf] = *(const bf16x8*)(xh + 32 * kf);
            Al[kf] = *(const bf16x8*)(xl + 32 * kf);
        }
        f32x4 acc[4];
#pragma unroll
        for (int nt = 0; nt < 4; ++nt)
            acc[nt] = (f32x4){bs[nt], bs[nt], bs[nt], bs[nt]};
#pragma unroll
        for (int kf = 0; kf < 4; ++kf) {
#pragma unroll
            for (int nt = 0; nt < 4; ++nt) {
                acc[nt] = __builtin_amdgcn_mfma_f32_16x16x32_bf16(Ah[kf], B[0][nt][kf], acc[nt], 0, 0, 0);
                acc[nt] = __builtin_amdgcn_mfma_f32_16x16x32_bf16(Ah[kf], B[1][nt][kf], acc[nt], 0, 0, 0);
                acc[nt] = __builtin_amdgcn_mfma_f32_16x16x32_bf16(Al[kf], B[0][nt][kf], acc[nt], 0, 0, 0);
            }
        }
        // D: row = m0 + 4*kq + j, col = 64*nhalf + 16*nt + r
#pragma unroll
        for (int nt = 0; nt < 4; ++nt) {
            int n = 64 * nhalf + 16 * nt + r;
            _Float16* yp = Y + (size_t)(m0 + 4 * kq) * DH + n;
#pragma unroll
            for (int j = 0; j < 4; ++j) {
                float v = acc[nt][j];
                if (RELU) v = fmaxf(v, 0.f);
                yp[(size_t)j * DH] = (_Float16)v;
            }
        }
    }
}

// ---------------- layer-3 projection: Z = (X * out_inv) @ W3   (N x 10) ----------------
__global__ __launch_bounds__(256) void proj_out(
        const _Float16* __restrict__ X, const float* __restrict__ out_inv,
        const float* __restrict__ W, float* __restrict__ Z, int N) {
    __shared__ float Wl[DH * 10];
    for (int i = threadIdx.x; i < DH * 10; i += blockDim.x) Wl[i] = W[i];
    __syncthreads();

    int lane = threadIdx.x & 63;
    int wid  = threadIdx.x >> 6;
    int wpb  = blockDim.x >> 6;
    int gw   = blockIdx.x * wpb + wid;
    int nw   = gridDim.x * wpb;

    for (int row = gw; row < N; row += nw) {
        float sc = out_inv[row];
        half2v xh = ((const half2v*)(X + (size_t)row * DH))[lane];
        float xx = (float)xh.x * sc;
        float xy = (float)xh.y * sc;
        float acc[10];
#pragma unroll
        for (int o = 0; o < 10; ++o)
            acc[o] = xx * Wl[(2 * lane) * 10 + o] + xy * Wl[(2 * lane + 1) * 10 + o];
#pragma unroll
        for (int off = 32; off > 0; off >>= 1) {
#pragma unroll
            for (int o = 0; o < 10; ++o)
                acc[o] += __shfl_down(acc[o], off);
        }
        if (lane == 0) {
#pragma unroll
            for (int o = 0; o < 10; ++o)
                Z[(size_t)row * 10 + o] = acc[o];
        }
    }
}

// ---------------- layer-3 aggregation: out[d] = in_inv[d]*sum Z[s] + b3 ----------------
__global__ void agg10(const float* __restrict__ Z, const int* __restrict__ row_off,
                      const int* __restrict__ csr_src, const float* __restrict__ in_inv,
                      const float* __restrict__ b, float* __restrict__ out, int N) {
    int r = blockIdx.x * blockDim.x + threadIdx.x;
    if (r >= N) return;
    float2 acc[5] = {};
    int start = row_off[r], end = row_off[r + 1];
    for (int e = start; e < end; ++e) {
        int s = csr_src[e];
        const float2* zp = (const float2*)(Z + (size_t)s * 10);
#pragma unroll
        for (int o = 0; o < 5; ++o) {
            float2 z = zp[o];
            acc[o].x += z.x; acc[o].y += z.y;
        }
    }
    float ii = in_inv[r];
#pragma unroll
    for (int o = 0; o < 5; ++o) {
        out[(size_t)r * 10 + 2 * o]     = acc[o].x * ii + b[2 * o];
        out[(size_t)r * 10 + 2 * o + 1] = acc[o].y * ii + b[2 * o + 1];
    }
}

extern "C" void kernel_launch(void* const* d_in, const int* in_sizes, int n_in,
                              void* d_out, int out_size, void* d_ws, size_t ws_size,
                              hipStream_t stream) {
    const float* features = (const float*)d_in[0];
    const int*   src      = (const int*)d_in[1];
    const int*   dst      = (const int*)d_in[2];
    const float* W0 = (const float*)d_in[3];
    const float* b0 = (const float*)d_in[4];
    const float* W1 = (const float*)d_in[5];
    const float* b1 = (const float*)d_in[6];
    const float* W2 = (const float*)d_in[7];
    const float* b2 = (const float*)d_in[8];
    const float* W3 = (const float*)d_in[9];
    const float* b3 = (const float*)d_in[10];
    float* out = (float*)d_out;

    char* ws = (char*)d_ws;
    int*   cnt_out = (int*)ws;                       // N
    int*   cnt_in  = cnt_out + NNODES;               // N
    int*   cursor  = cnt_in + NNODES;                // N
    int*   row_off = cursor + NNODES;                // N+1
    int*   bsums   = row_off + NNODES + 1;           // SCAN_BLOCKS
    float* out_inv = (float*)(bsums + SCAN_BLOCKS);  // N
    float* in_inv  = out_inv + NNODES;               // N
    int*   csr_src = (int*)(in_inv + NNODES);        // E
    size_t metaInts = (size_t)(6 * NNODES + 1 + SCAN_BLOCKS) + NEDGES;
    size_t off = ((metaInts * 4 + 255) / 256) * 256;
    ushort* WThi = (ushort*)(ws + off);  off += 3 * DH * DH * sizeof(ushort);
    ushort* WTlo = (ushort*)(ws + off);  off += 3 * DH * DH * sizeof(ushort);
    off = ((off + 255) / 256) * 256;
    ushort* Xhi = (ushort*)(ws + off);     off += (size_t)NNODES * DH * sizeof(ushort);
    ushort* Xlo = (ushort*)(ws + off);     off += (size_t)NNODES * DH * sizeof(ushort);
    _Float16* F16 = (_Float16*)(ws + off); off += (size_t)NNODES * DH * sizeof(_Float16);
    _Float16* Y16 = (_Float16*)(ws + off); off += (size_t)NNODES * DH * sizeof(_Float16);
    float*  Z   = (float*)Xhi;             // reused for layer-3 projection (N x 10)

    // ---- CSR build + norms + W conversion + feature fp16 (once per call) ----
    hipMemsetAsync(cnt_out, 0, 2 * NNODES * sizeof(int), stream);
    deg_count<<<(NEDGES + 255) / 256, 256, 0, stream>>>(src, dst, cnt_out, cnt_in, NEDGES);
    scan_sums<<<SCAN_BLOCKS, SCAN_THREADS, 0, stream>>>(cnt_in, bsums, NNODES);
    scan_final<<<SCAN_BLOCKS, SCAN_THREADS, 0, stream>>>(cnt_in, bsums, row_off, NNODES, SCAN_BLOCKS);
    inv_kernel<<<(NNODES + 255) / 256, 256, 0, stream>>>(cnt_out, cnt_in, row_off, cursor, out_inv, in_inv, NNODES);
    scatter_kernel<<<(NEDGES + 255) / 256, 256, 0, stream>>>(src, dst, cursor, csr_src, NEDGES);
    wconv<<<(3 * DH * DH + 255) / 256, 256, 0, stream>>>(W0, W1, W2, WThi, WTlo);
    f32_to_f16<<<(NNODES * DH / 4 + 255) / 256, 256, 0, stream>>>(features, F16, NNODES * DH / 4);

    const int spmm_blocks = (NNODES / 2 + 3) / 4;
    const int Mtiles = NNODES / 16;                 // 3125
    const int gemm_blocks = 512;

    // Layer 0
    spmm_csr<<<spmm_blocks, 256, 0, stream>>>(F16, row_off, csr_src, out_inv, in_inv, Xhi, Xlo, NNODES);
    gemm_mfma<1><<<gemm_blocks, 256, 0, stream>>>(Xhi, Xlo, WThi, WTlo, b0, Y16, Mtiles);
    // Layer 1
    spmm_csr<<<spmm_blocks, 256, 0, stream>>>(Y16, row_off, csr_src, out_inv, in_inv, Xhi, Xlo, NNODES);
    gemm_mfma<1><<<gemm_blocks, 256, 0, stream>>>(Xhi, Xlo, WThi + DH * DH, WTlo + DH * DH, b1, Y16, Mtiles);
    // Layer 2
    spmm_csr<<<spmm_blocks, 256, 0, stream>>>(Y16, row_off, csr_src, out_inv, in_inv, Xhi, Xlo, NNODES);
    gemm_mfma<1><<<gemm_blocks, 256, 0, stream>>>(Xhi, Xlo, WThi + 2 * DH * DH, WTlo + 2 * DH * DH, b2, Y16, Mtiles);
    // Layer 3: project to O=10 first, then aggregate 10-wide
    proj_out<<<512, 256, 0, stream>>>(Y16, out_inv, W3, Z, NNODES);
    agg10<<<(NNODES + 255) / 256, 256, 0, stream>>>(Z, row_off, csr_src, in_inv, b3, out, NNODES);
}

// Round 19
// 297.291 us; speedup vs baseline: 1.0470x; 1.0470x over previous
//
#include <hip/hip_runtime.h>

#define NNODES 50000
#define NEDGES 600000
#define DH 128
#define SCAN_THREADS 512
#define SCAN_ELEMS 2048
#define SCAN_BLOCKS ((NNODES + SCAN_ELEMS - 1) / SCAN_ELEMS)   // 25
#define WCONV_BLOCKS ((3 * DH * DH) / 256)                     // 192

typedef __attribute__((ext_vector_type(8))) short bf16x8;
typedef __attribute__((ext_vector_type(4))) float f32x4;
typedef __attribute__((ext_vector_type(4))) _Float16 half4;
typedef __attribute__((ext_vector_type(2))) _Float16 half2v;

__device__ __forceinline__ ushort f2bf(float x) {
    uint u = __float_as_uint(x);
    uint r = (u + 0x7FFF + ((u >> 16) & 1)) >> 16;
    return (ushort)r;
}
__device__ __forceinline__ float bf2f(ushort h) {
    return __uint_as_float(((uint)h) << 16);
}

// ---------------- degree count (int atomics) ----------------
__global__ void deg_count(const int* __restrict__ src, const int* __restrict__ dst,
                          int* __restrict__ cnt_out, int* __restrict__ cnt_in, int E) {
    int i = blockIdx.x * blockDim.x + threadIdx.x;
    if (i < E) {
        atomicAdd(&cnt_out[src[i]], 1);
        atomicAdd(&cnt_in[dst[i]], 1);
    }
}

// ---------------- multi-block scan, phase 1: per-block sums ----------------
__global__ __launch_bounds__(SCAN_THREADS) void scan_sums(
        const int* __restrict__ counts, int* __restrict__ bsums, int N) {
    __shared__ int red[SCAN_THREADS / 64];
    int b = blockIdx.x, t = threadIdx.x;
    int base = b * SCAN_ELEMS + t * 4;
    int s = 0;
    if (base + 3 < N) {
        int4 v = *(const int4*)(counts + base);
        s = v.x + v.y + v.z + v.w;
    } else {
        for (int j = 0; j < 4; ++j) if (base + j < N) s += counts[base + j];
    }
#pragma unroll
    for (int off = 32; off > 0; off >>= 1) s += __shfl_down(s, off);
    if ((t & 63) == 0) red[t >> 6] = s;
    __syncthreads();
    if (t == 0) {
        int tot = 0;
#pragma unroll
        for (int w = 0; w < SCAN_THREADS / 64; ++w) tot += red[w];
        bsums[b] = tot;
    }
}

// ---------------- scan phase 2 + norms + cursor init (fused) ----------------
__global__ __launch_bounds__(SCAN_THREADS) void scan_final(
        const int* __restrict__ counts, const int* __restrict__ bsums,
        const int* __restrict__ cnt_out, int* __restrict__ off,
        int* __restrict__ cursor, float* __restrict__ out_inv,
        float* __restrict__ in_inv, int N, int nb) {
    __shared__ int lds[SCAN_THREADS];
    __shared__ int base_s;
    int b = blockIdx.x, t = threadIdx.x;
    if (t == 0) {
        int acc = 0;
        for (int i = 0; i < b; ++i) acc += bsums[i];
        base_s = acc;
    }
    int i0 = b * SCAN_ELEMS + t * 4;
    int v[4]; int s = 0;
#pragma unroll
    for (int j = 0; j < 4; ++j) {
        int idx = i0 + j;
        v[j] = (idx < N) ? counts[idx] : 0;
        s += v[j];
    }
    lds[t] = s;
    __syncthreads();
    for (int d = 1; d < SCAN_THREADS; d <<= 1) {
        int x = lds[t];
        int y = (t >= d) ? lds[t - d] : 0;
        __syncthreads();
        lds[t] = x + y;
        __syncthreads();
    }
    int excl = (t == 0) ? 0 : lds[t - 1];
    int run = base_s + excl;
#pragma unroll
    for (int j = 0; j < 4; ++j) {
        int idx = i0 + j;
        if (idx < N) {
            off[idx]    = run;
            cursor[idx] = run;
            in_inv[idx]  = rsqrtf(fmaxf((float)v[j], 1.0f));
            out_inv[idx] = rsqrtf(fmaxf((float)cnt_out[idx], 1.0f));
        }
        run += v[j];
    }
    if (b == nb - 1 && t == SCAN_THREADS - 1) off[N] = run;
}

// ---------------- scatter edges into dst-CSR (cursor atomics, proven) ----------------
__global__ void scatter_kernel(const int* __restrict__ src, const int* __restrict__ dst,
                               int* __restrict__ cursor, int* __restrict__ csr_src, int E) {
    int i = blockIdx.x * blockDim.x + threadIdx.x;
    if (i < E) {
        int pos = atomicAdd(&cursor[dst[i]], 1);
        csr_src[pos] = src[i];
    }
}

// ---------------- prep: wconv (blocks [0,192)) + features fp32->fp16 (rest) ----------------
__global__ void prep_kernel(const float* __restrict__ W0, const float* __restrict__ W1,
                            const float* __restrict__ W2,
                            ushort* __restrict__ WThi, ushort* __restrict__ WTlo,
                            const float* __restrict__ fin, _Float16* __restrict__ fout,
                            int n4) {
    if (blockIdx.x < WCONV_BLOCKS) {
        int t = blockIdx.x * blockDim.x + threadIdx.x;   // < 3*DH*DH
        int L = t >> 14;
        int idx = t & (DH * DH - 1);
        int n = idx >> 7;
        int k = idx & 127;
        const float* W = (L == 0) ? W0 : ((L == 1) ? W1 : W2);
        float w = W[k * DH + n];
        ushort hi = f2bf(w);
        float lof = w - bf2f(hi);
        WThi[t] = hi;
        WTlo[t] = f2bf(lof);
    } else {
        int i = (blockIdx.x - WCONV_BLOCKS) * blockDim.x + threadIdx.x;
        if (i < n4) {
            float4 v = ((const float4*)fin)[i];
            half4 h = {(_Float16)v.x, (_Float16)v.y, (_Float16)v.z, (_Float16)v.w};
            ((half4*)fout)[i] = h;
        }
    }
}

// ---------------- SpMM (gather fp16), half-wave per dst row, unroll x4 ----------------
// agg[d] = in_inv[d] * sum_{s in N(d)} out_inv[s]*h[s]; emits split-bf16
__global__ __launch_bounds__(256) void spmm_csr(
        const _Float16* __restrict__ h, const int* __restrict__ row_off,
        const int* __restrict__ csr_src, const float* __restrict__ out_inv,
        const float* __restrict__ in_inv,
        ushort* __restrict__ Xhi, ushort* __restrict__ Xlo, int N) {
    int gw   = (blockIdx.x * blockDim.x + threadIdx.x) >> 6;
    int lane = threadIdx.x & 63;
    int half = lane >> 5;          // two rows per wave
    int l5   = lane & 31;          // 32 lanes x 8B = 256B row
    int row  = gw * 2 + half;
    if (row >= N) return;
    int start = row_off[row], end = row_off[row + 1];
    float4 acc0 = make_float4(0.f, 0.f, 0.f, 0.f);
    float4 acc1 = make_float4(0.f, 0.f, 0.f, 0.f);
    int e = start;
    for (; e + 4 <= end; e += 4) {
        int s0 = csr_src[e];
        int s1 = csr_src[e + 1];
        int s2 = csr_src[e + 2];
        int s3 = csr_src[e + 3];
        float sc0 = out_inv[s0];
        float sc1 = out_inv[s1];
        float sc2 = out_inv[s2];
        float sc3 = out_inv[s3];
        half4 v0 = ((const half4*)(h + (size_t)s0 * DH))[l5];
        half4 v1 = ((const half4*)(h + (size_t)s1 * DH))[l5];
        half4 v2 = ((const half4*)(h + (size_t)s2 * DH))[l5];
        half4 v3 = ((const half4*)(h + (size_t)s3 * DH))[l5];
        acc0.x += (float)v0.x * sc0; acc0.y += (float)v0.y * sc0;
        acc0.z += (float)v0.z * sc0; acc0.w += (float)v0.w * sc0;
        acc1.x += (float)v1.x * sc1; acc1.y += (float)v1.y * sc1;
        acc1.z += (float)v1.z * sc1; acc1.w += (float)v1.w * sc1;
        acc0.x += (float)v2.x * sc2; acc0.y += (float)v2.y * sc2;
        acc0.z += (float)v2.z * sc2; acc0.w += (float)v2.w * sc2;
        acc1.x += (float)v3.x * sc3; acc1.y += (float)v3.y * sc3;
        acc1.z += (float)v3.z * sc3; acc1.w += (float)v3.w * sc3;
    }
    for (; e < end; ++e) {
        int s0 = csr_src[e];
        float sc0 = out_inv[s0];
        half4 v0 = ((const half4*)(h + (size_t)s0 * DH))[l5];
        acc0.x += (float)v0.x * sc0; acc0.y += (float)v0.y * sc0;
        acc0.z += (float)v0.z * sc0; acc0.w += (float)v0.w * sc0;
    }
    float ii = in_inv[row];
    float4 acc;
    acc.x = (acc0.x + acc1.x) * ii;
    acc.y = (acc0.y + acc1.y) * ii;
    acc.z = (acc0.z + acc1.z) * ii;
    acc.w = (acc0.w + acc1.w) * ii;

    ushort4 hi, lo;
    hi.x = f2bf(acc.x); lo.x = f2bf(acc.x - bf2f(hi.x));
    hi.y = f2bf(acc.y); lo.y = f2bf(acc.y - bf2f(hi.y));
    hi.z = f2bf(acc.z); lo.z = f2bf(acc.z - bf2f(hi.z));
    hi.w = f2bf(acc.w); lo.w = f2bf(acc.w - bf2f(hi.w));
    ((ushort4*)(Xhi + (size_t)row * DH))[l5] = hi;
    ((ushort4*)(Xlo + (size_t)row * DH))[l5] = lo;
}

// ---------------- MFMA GEMM: Yf16 = relu(X @ W + b), split-bf16 3-pass ----------------
template<int RELU>
__global__ __launch_bounds__(256, 2) void gemm_mfma(
        const ushort* __restrict__ Xhi, const ushort* __restrict__ Xlo,
        const ushort* __restrict__ WThi, const ushort* __restrict__ WTlo,
        const float* __restrict__ bias, _Float16* __restrict__ Y, int Mtiles) {
    int lane  = threadIdx.x & 63;
    int gwave = (blockIdx.x * blockDim.x + threadIdx.x) >> 6;
    int nwav  = (gridDim.x * blockDim.x) >> 6;
    int nhalf = gwave & 1;
    int wstart  = gwave >> 1;
    int wstride = nwav >> 1;

    int r  = lane & 15;
    int kq = lane >> 4;

    bf16x8 B[2][4][4];
#pragma unroll
    for (int nt = 0; nt < 4; ++nt) {
        int n = 64 * nhalf + 16 * nt + r;
#pragma unroll
        for (int kf = 0; kf < 4; ++kf) {
            B[0][nt][kf] = *(const bf16x8*)(WThi + n * DH + 32 * kf + 8 * kq);
            B[1][nt][kf] = *(const bf16x8*)(WTlo + n * DH + 32 * kf + 8 * kq);
        }
    }
    float bs[4];
#pragma unroll
    for (int nt = 0; nt < 4; ++nt) bs[nt] = bias[64 * nhalf + 16 * nt + r];

    for (int mt = wstart; mt < Mtiles; mt += wstride) {
        int m0 = mt * 16;
        const ushort* xh = Xhi + (size_t)(m0 + r) * DH + 8 * kq;
        const ushort* xl = Xlo + (size_t)(m0 + r) * DH + 8 * kq;
        bf16x8 Ah[4], Al[4];
#pragma unroll
        for (int kf = 0; kf < 4; ++kf) {
            Ah[kf] = *(const bf16x8*)(xh + 32 * kf);
            Al[kf] = *(const bf16x8*)(xl + 32 * kf);
        }
        f32x4 acc[4];
#pragma unroll
        for (int nt = 0; nt < 4; ++nt)
            acc[nt] = (f32x4){bs[nt], bs[nt], bs[nt], bs[nt]};
#pragma unroll
        for (int kf = 0; kf < 4; ++kf) {
#pragma unroll
            for (int nt = 0; nt < 4; ++nt) {
                acc[nt] = __builtin_amdgcn_mfma_f32_16x16x32_bf16(Ah[kf], B[0][nt][kf], acc[nt], 0, 0, 0);
                acc[nt] = __builtin_amdgcn_mfma_f32_16x16x32_bf16(Ah[kf], B[1][nt][kf], acc[nt], 0, 0, 0);
                acc[nt] = __builtin_amdgcn_mfma_f32_16x16x32_bf16(Al[kf], B[0][nt][kf], acc[nt], 0, 0, 0);
            }
        }
        // D: row = m0 + 4*kq + j, col = 64*nhalf + 16*nt + r
#pragma unroll
        for (int nt = 0; nt < 4; ++nt) {
            int n = 64 * nhalf + 16 * nt + r;
            _Float16* yp = Y + (size_t)(m0 + 4 * kq) * DH + n;
#pragma unroll
            for (int j = 0; j < 4; ++j) {
                float v = acc[nt][j];
                if (RELU) v = fmaxf(v, 0.f);
                yp[(size_t)j * DH] = (_Float16)v;
            }
        }
    }
}

// ---------------- layer-3 projection: Z = (X * out_inv) @ W3   (N x 10) ----------------
__global__ __launch_bounds__(256) void proj_out(
        const _Float16* __restrict__ X, const float* __restrict__ out_inv,
        const float* __restrict__ W, float* __restrict__ Z, int N) {
    __shared__ float Wl[DH * 10];
    for (int i = threadIdx.x; i < DH * 10; i += blockDim.x) Wl[i] = W[i];
    __syncthreads();

    int lane = threadIdx.x & 63;
    int wid  = threadIdx.x >> 6;
    int wpb  = blockDim.x >> 6;
    int gw   = blockIdx.x * wpb + wid;
    int nw   = gridDim.x * wpb;

    for (int row = gw; row < N; row += nw) {
        float sc = out_inv[row];
        half2v xh = ((const half2v*)(X + (size_t)row * DH))[lane];
        float xx = (float)xh.x * sc;
        float xy = (float)xh.y * sc;
        float acc[10];
#pragma unroll
        for (int o = 0; o < 10; ++o)
            acc[o] = xx * Wl[(2 * lane) * 10 + o] + xy * Wl[(2 * lane + 1) * 10 + o];
#pragma unroll
        for (int off = 32; off > 0; off >>= 1) {
#pragma unroll
            for (int o = 0; o < 10; ++o)
                acc[o] += __shfl_down(acc[o], off);
        }
        if (lane == 0) {
#pragma unroll
            for (int o = 0; o < 10; ++o)
                Z[(size_t)row * 10 + o] = acc[o];
        }
    }
}

// ---------------- layer-3 aggregation: out[d] = in_inv[d]*sum Z[s] + b3 ----------------
__global__ void agg10(const float* __restrict__ Z, const int* __restrict__ row_off,
                      const int* __restrict__ csr_src, const float* __restrict__ in_inv,
                      const float* __restrict__ b, float* __restrict__ out, int N) {
    int r = blockIdx.x * blockDim.x + threadIdx.x;
    if (r >= N) return;
    float2 acc[5] = {};
    int start = row_off[r], end = row_off[r + 1];
    for (int e = start; e < end; ++e) {
        int s = csr_src[e];
        const float2* zp = (const float2*)(Z + (size_t)s * 10);
#pragma unroll
        for (int o = 0; o < 5; ++o) {
            float2 z = zp[o];
            acc[o].x += z.x; acc[o].y += z.y;
        }
    }
    float ii = in_inv[r];
#pragma unroll
    for (int o = 0; o < 5; ++o) {
        out[(size_t)r * 10 + 2 * o]     = acc[o].x * ii + b[2 * o];
        out[(size_t)r * 10 + 2 * o + 1] = acc[o].y * ii + b[2 * o + 1];
    }
}

extern "C" void kernel_launch(void* const* d_in, const int* in_sizes, int n_in,
                              void* d_out, int out_size, void* d_ws, size_t ws_size,
                              hipStream_t stream) {
    const float* features = (const float*)d_in[0];
    const int*   src      = (const int*)d_in[1];
    const int*   dst      = (const int*)d_in[2];
    const float* W0 = (const float*)d_in[3];
    const float* b0 = (const float*)d_in[4];
    const float* W1 = (const float*)d_in[5];
    const float* b1 = (const float*)d_in[6];
    const float* W2 = (const float*)d_in[7];
    const float* b2 = (const float*)d_in[8];
    const float* W3 = (const float*)d_in[9];
    const float* b3 = (const float*)d_in[10];
    float* out = (float*)d_out;

    char* ws = (char*)d_ws;
    int*   cnt_out = (int*)ws;                       // N
    int*   cnt_in  = cnt_out + NNODES;               // N
    int*   cursor  = cnt_in + NNODES;                // N
    int*   row_off = cursor + NNODES;                // N+1
    int*   bsums   = row_off + NNODES + 1;           // SCAN_BLOCKS
    float* out_inv = (float*)(bsums + SCAN_BLOCKS);  // N
    float* in_inv  = out_inv + NNODES;               // N
    int*   csr_src = (int*)(in_inv + NNODES);        // E
    size_t metaInts = (size_t)(6 * NNODES + 1 + SCAN_BLOCKS) + NEDGES;
    size_t off = ((metaInts * 4 + 255) / 256) * 256;
    ushort* WThi = (ushort*)(ws + off);  off += 3 * DH * DH * sizeof(ushort);
    ushort* WTlo = (ushort*)(ws + off);  off += 3 * DH * DH * sizeof(ushort);
    off = ((off + 255) / 256) * 256;
    ushort* Xhi = (ushort*)(ws + off);     off += (size_t)NNODES * DH * sizeof(ushort);
    ushort* Xlo = (ushort*)(ws + off);     off += (size_t)NNODES * DH * sizeof(ushort);
    _Float16* F16 = (_Float16*)(ws + off); off += (size_t)NNODES * DH * sizeof(_Float16);
    _Float16* Y16 = (_Float16*)(ws + off); off += (size_t)NNODES * DH * sizeof(_Float16);
    float*  Z   = (float*)Xhi;             // reused for layer-3 projection (N x 10)

    const int n4 = NNODES * DH / 4;

    // ---- CSR build + norms + W conversion + feature fp16 (once per call) ----
    hipMemsetAsync(cnt_out, 0, 2 * NNODES * sizeof(int), stream);
    deg_count<<<(NEDGES + 255) / 256, 256, 0, stream>>>(src, dst, cnt_out, cnt_in, NEDGES);
    scan_sums<<<SCAN_BLOCKS, SCAN_THREADS, 0, stream>>>(cnt_in, bsums, NNODES);
    scan_final<<<SCAN_BLOCKS, SCAN_THREADS, 0, stream>>>(cnt_in, bsums, cnt_out, row_off,
                                                         cursor, out_inv, in_inv, NNODES, SCAN_BLOCKS);
    scatter_kernel<<<(NEDGES + 255) / 256, 256, 0, stream>>>(src, dst, cursor, csr_src, NEDGES);
    prep_kernel<<<WCONV_BLOCKS + (n4 + 255) / 256, 256, 0, stream>>>(W0, W1, W2, WThi, WTlo,
                                                                     features, F16, n4);

    const int spmm_blocks = (NNODES / 2 + 3) / 4;
    const int Mtiles = NNODES / 16;                 // 3125
    const int gemm_blocks = 512;

    // Layer 0
    spmm_csr<<<spmm_blocks, 256, 0, stream>>>(F16, row_off, csr_src, out_inv, in_inv, Xhi, Xlo, NNODES);
    gemm_mfma<1><<<gemm_blocks, 256, 0, stream>>>(Xhi, Xlo, WThi, WTlo, b0, Y16, Mtiles);
    // Layer 1
    spmm_csr<<<spmm_blocks, 256, 0, stream>>>(Y16, row_off, csr_src, out_inv, in_inv, Xhi, Xlo, NNODES);
    gemm_mfma<1><<<gemm_blocks, 256, 0, stream>>>(Xhi, Xlo, WThi + DH * DH, WTlo + DH * DH, b1, Y16, Mtiles);
    // Layer 2
    spmm_csr<<<spmm_blocks, 256, 0, stream>>>(Y16, row_off, csr_src, out_inv, in_inv, Xhi, Xlo, NNODES);
    gemm_mfma<1><<<gemm_blocks, 256, 0, stream>>>(Xhi, Xlo, WThi + 2 * DH * DH, WTlo + 2 * DH * DH, b2, Y16, Mtiles);
    // Layer 3: project to O=10 first, then aggregate 10-wide
    proj_out<<<512, 256, 0, stream>>>(Y16, out_inv, W3, Z, NNODES);
    agg10<<<(NNODES + 255) / 256, 256, 0, stream>>>(Z, row_off, csr_src, in_inv, b3, out, NNODES);
}